// Round 1
// baseline (1216.975 us; speedup 1.0000x reference)
//
#include <hip/hip_runtime.h>
#include <math.h>

#define B_  4
#define H_  16
#define S_  1024
#define DK_ 64

constexpr float SCALE = 0.125f;     // 1/sqrt(64)
constexpr float NEGV  = -1.0e9f;

#define RPW   16                    // query rows per wave
#define WAVES 4
#define RPB   (RPW * WAVES)         // 64 rows per block
#define NT    (S_ / 64)             // 16 column tiles of 64

__device__ __forceinline__ float wave_max(float v) {
#pragma unroll
    for (int off = 32; off >= 1; off >>= 1)
        v = fmaxf(v, __shfl_xor(v, off, 64));
    return v;
}

__device__ __forceinline__ float wave_sum(float v) {
#pragma unroll
    for (int off = 32; off >= 1; off >>= 1)
        v += __shfl_xor(v, off, 64);
    return v;
}

__launch_bounds__(256, 4)
__global__ void mha_scores_softmax(const float* __restrict__ q,
                                   const float* __restrict__ k,
                                   const int*   __restrict__ mask,
                                   float* __restrict__ attn_out,
                                   float* __restrict__ scores_out)
{
    const int bh   = blockIdx.y;                 // 0..63 (b*16+h)
    const int b    = bh >> 4;
    const int lane = threadIdx.x & 63;
    const int w    = __builtin_amdgcn_readfirstlane(threadIdx.x >> 6);
    const int row0 = blockIdx.x * RPB + w * RPW;

    const float* qbase = q + ((size_t)bh * S_ + row0) * DK_;
    const float* kbase = k + (size_t)bh * S_ * DK_;
    const int*   mbase = mask + ((size_t)b * S_ + row0) * S_;
    float* srow = scores_out + ((size_t)bh * S_ + row0) * S_;
    float* arow = attn_out   + ((size_t)bh * S_ + row0) * S_;

    float mx[RPW];
#pragma unroll
    for (int r = 0; r < RPW; ++r) mx[r] = -INFINITY;

    // ---- Phase A: scores = mask(QK^T * scale); write scores; per-lane max ----
    for (int t = 0; t < NT; ++t) {
        const int col = (t << 6) + lane;
        const float* kp = kbase + (size_t)col * DK_;
        float s[RPW];
#pragma unroll
        for (int r = 0; r < RPW; ++r) s[r] = 0.0f;

#pragma unroll
        for (int ds = 0; ds < DK_ / 4; ++ds) {
            const float4 kv = *(const float4*)(kp + (ds << 2));
#pragma unroll
            for (int r = 0; r < RPW; ++r) {
                // qbase + uniform offset: wave-uniform -> scalar loads (SMEM pipe)
                const float4 qv = *(const float4*)(qbase + r * DK_ + (ds << 2));
                s[r] = fmaf(qv.x, kv.x, s[r]);
                s[r] = fmaf(qv.y, kv.y, s[r]);
                s[r] = fmaf(qv.z, kv.z, s[r]);
                s[r] = fmaf(qv.w, kv.w, s[r]);
            }
        }

#pragma unroll
        for (int r = 0; r < RPW; ++r) {
            const int mv = mbase[(size_t)r * S_ + col];
            float sv = s[r] * SCALE;
            sv = (mv == 0) ? NEGV : sv;
            srow[(size_t)r * S_ + col] = sv;   // coalesced across lanes
            mx[r] = fmaxf(mx[r], sv);
        }
    }

    float m[RPW], l[RPW];
#pragma unroll
    for (int r = 0; r < RPW; ++r) { m[r] = wave_max(mx[r]); l[r] = 0.0f; }

    // ---- Phase A2: sum of exp (re-read scores; L2-hot, same thread wrote them) ----
    for (int t = 0; t < NT; ++t) {
        const int col = (t << 6) + lane;
#pragma unroll
        for (int r = 0; r < RPW; ++r) {
            const float sv = srow[(size_t)r * S_ + col];
            l[r] += __expf(sv - m[r]);
        }
    }

    float inv[RPW];
#pragma unroll
    for (int r = 0; r < RPW; ++r) inv[r] = 1.0f / wave_sum(l[r]);

    // ---- Phase B: attn = exp(s - m) / l ----
    for (int t = 0; t < NT; ++t) {
        const int col = (t << 6) + lane;
#pragma unroll
        for (int r = 0; r < RPW; ++r) {
            const float sv = srow[(size_t)r * S_ + col];
            arow[(size_t)r * S_ + col] = __expf(sv - m[r]) * inv[r];
        }
    }
}

extern "C" void kernel_launch(void* const* d_in, const int* in_sizes, int n_in,
                              void* d_out, int out_size, void* d_ws, size_t ws_size,
                              hipStream_t stream) {
    const float* q    = (const float*)d_in[0];
    const float* k    = (const float*)d_in[1];
    // d_in[2] = value: unused by the reference outputs (attn, scores)
    const int*   mask = (const int*)d_in[3];

    float* out    = (float*)d_out;
    float* attn   = out;                                   // (B,H,S,S)
    float* scores = out + (size_t)B_ * H_ * S_ * S_;       // (B,H,S,S)

    dim3 grid(S_ / RPB, B_ * H_);   // (16, 64)
    mha_scores_softmax<<<grid, dim3(256), 0, stream>>>(q, k, mask, attn, scores);
}

// Round 2
// 1098.234 us; speedup vs baseline: 1.1081x; 1.1081x over previous
//
#include <hip/hip_runtime.h>
#include <math.h>

#define B_  4
#define H_  16
#define S_  1024
#define DK_ 64

constexpr float SCALE = 0.125f;     // 1/sqrt(64)
constexpr float NEGV  = -1.0e9f;

#define RPW   4                     // query rows per wave
#define WAVES 4
#define RPB   (RPW * WAVES)         // 16 rows per block
#define NT    (S_ / 64)             // 16 column tiles of 64

__device__ __forceinline__ float wave_max(float v) {
#pragma unroll
    for (int off = 32; off >= 1; off >>= 1)
        v = fmaxf(v, __shfl_xor(v, off, 64));
    return v;
}

__device__ __forceinline__ float wave_sum(float v) {
#pragma unroll
    for (int off = 32; off >= 1; off >>= 1)
        v += __shfl_xor(v, off, 64);
    return v;
}

__launch_bounds__(256, 2)
__global__ void mha_scores_softmax(const float* __restrict__ q,
                                   const float* __restrict__ k,
                                   const int*   __restrict__ mask,
                                   float* __restrict__ attn_out,
                                   float* __restrict__ scores_out)
{
    // Wave-private score stash: 4 waves x 4 rows x 1024 cols x 4B = 64 KB.
    // Each wave only ever touches its own [w] slice -> NO __syncthreads needed.
    __shared__ float sc[WAVES][RPW][S_];

    const int bh   = blockIdx.y;                 // 0..63 (b*16+h)
    const int b    = bh >> 4;
    const int lane = threadIdx.x & 63;
    const int w    = __builtin_amdgcn_readfirstlane(threadIdx.x >> 6);
    const int row0 = blockIdx.x * RPB + w * RPW;

    const float* qbase = q + ((size_t)bh * S_ + row0) * DK_;   // wave-uniform
    const float* kbase = k + (size_t)bh * S_ * DK_;
    const int*   mbase = mask + ((size_t)b * S_ + row0) * S_;
    float* srow = scores_out + ((size_t)bh * S_ + row0) * S_;
    float* arow = attn_out   + ((size_t)bh * S_ + row0) * S_;

    float mx[RPW];
#pragma unroll
    for (int r = 0; r < RPW; ++r) mx[r] = -INFINITY;

    // ---- Phase A: scores = mask(QK^T * scale); write global + LDS; track max ----
    for (int t = 0; t < NT; ++t) {
        const int col = (t << 6) + lane;
        const float* kp = kbase + (size_t)col * DK_;
        float acc[RPW];
#pragma unroll
        for (int r = 0; r < RPW; ++r) acc[r] = 0.0f;

#pragma unroll
        for (int ds = 0; ds < DK_ / 4; ++ds) {
            const float4 kv = *(const float4*)(kp + (ds << 2));
#pragma unroll
            for (int r = 0; r < RPW; ++r) {
                // wave-uniform address -> scalar (s_load) on the SMEM pipe
                const float4 qv = *(const float4*)(qbase + r * DK_ + (ds << 2));
                acc[r] = fmaf(qv.x, kv.x, acc[r]);
                acc[r] = fmaf(qv.y, kv.y, acc[r]);
                acc[r] = fmaf(qv.z, kv.z, acc[r]);
                acc[r] = fmaf(qv.w, kv.w, acc[r]);
            }
        }

#pragma unroll
        for (int r = 0; r < RPW; ++r) {
            const int mv = mbase[(size_t)r * S_ + col];
            float sv = acc[r] * SCALE;
            sv = (mv == 0) ? NEGV : sv;
            srow[(size_t)r * S_ + col] = sv;   // coalesced stream-out
            sc[w][r][col] = sv;                // LDS stash (bank = lane%32, 2-way = free)
            mx[r] = fmaxf(mx[r], sv);
        }
    }

    float m[RPW], l[RPW];
#pragma unroll
    for (int r = 0; r < RPW; ++r) { m[r] = wave_max(mx[r]); l[r] = 0.0f; }

    // ---- Phase A2: sum of exp from LDS ----
    for (int t = 0; t < NT; ++t) {
        const int col = (t << 6) + lane;
#pragma unroll
        for (int r = 0; r < RPW; ++r)
            l[r] += __expf(sc[w][r][col] - m[r]);
    }

    float inv[RPW];
#pragma unroll
    for (int r = 0; r < RPW; ++r) inv[r] = 1.0f / wave_sum(l[r]);

    // ---- Phase B: attn = exp(s - m) / l from LDS ----
    for (int t = 0; t < NT; ++t) {
        const int col = (t << 6) + lane;
#pragma unroll
        for (int r = 0; r < RPW; ++r)
            arow[(size_t)r * S_ + col] = __expf(sc[w][r][col] - m[r]) * inv[r];
    }
}

extern "C" void kernel_launch(void* const* d_in, const int* in_sizes, int n_in,
                              void* d_out, int out_size, void* d_ws, size_t ws_size,
                              hipStream_t stream) {
    const float* q    = (const float*)d_in[0];
    const float* k    = (const float*)d_in[1];
    // d_in[2] = value: unused by the reference outputs (attn, scores)
    const int*   mask = (const int*)d_in[3];

    float* out    = (float*)d_out;
    float* attn   = out;                                   // (B,H,S,S)
    float* scores = out + (size_t)B_ * H_ * S_ * S_;       // (B,H,S,S)

    dim3 grid(S_ / RPB, B_ * H_);   // (64, 64)
    mha_scores_softmax<<<grid, dim3(256), 0, stream>>>(q, k, mask, attn, scores);
}